// Round 8
// baseline (210.061 us; speedup 1.0000x reference)
//
#include <hip/hip_runtime.h>
#include <stdint.h>

#define B_TOT 16384
#define IN_DIM 128
#define H1 256
#define H2 128
#define NC 10

// LDS byte layout: W2T rows 0..127 [128][128] f32 | WoT [128][10] f32 | scr
#define W2TL_BYTES (128 * H2 * 4)          // 65536
#define WOT_OFF    W2TL_BYTES
#define WOT_BYTES  (H2 * NC * 4)           // 5120
#define SCR_OFF    (WOT_OFF + WOT_BYTES)   // 70656
#define LDS_BYTES  (SCR_OFF + 16 * 1024)   // 87040

#define ZG 131072  // byte offset (rel. W2Tg) of the global zero row

typedef float v2f __attribute__((ext_vector_type(2)));

// ---------------------------------------------------------------------------
// Kernel A: cur1[b][n] = sum_k x[b][k]*W1[n][k] + b1[n]   (r2 version)
// ---------------------------------------------------------------------------
__global__ __launch_bounds__(256) void gemm1_kernel(
    const float* __restrict__ x, const float* __restrict__ W1,
    const float* __restrict__ b1, float* __restrict__ cur1) {
  __shared__ float xs[16 * 128];
  const int tid = threadIdx.x;
  const long row0 = (long)blockIdx.x * 16;

  const float4* xt = (const float4*)(x + row0 * IN_DIM);
  float4* xs4 = (float4*)xs;
  xs4[tid] = xt[tid];
  xs4[tid + 256] = xt[tid + 256];
  __syncthreads();

  const int n = tid;
  float acc[16];
#pragma unroll
  for (int r = 0; r < 16; ++r) acc[r] = 0.f;

  const float* wrow = W1 + n * IN_DIM;
  for (int k0 = 0; k0 < IN_DIM; k0 += 4) {
    const float4 wv = *(const float4*)(wrow + k0);
#pragma unroll
    for (int r = 0; r < 16; ++r) {
      const float4 xv = *(const float4*)(xs + r * IN_DIM + k0);
      acc[r] = fmaf(wv.x, xv.x, acc[r]);
      acc[r] = fmaf(wv.y, xv.y, acc[r]);
      acc[r] = fmaf(wv.z, xv.z, acc[r]);
      acc[r] = fmaf(wv.w, xv.w, acc[r]);
    }
  }
  const float bias = b1[n];
#pragma unroll
  for (int r = 0; r < 16; ++r)
    cur1[(row0 + r) * H1 + n] = acc[r] + bias;
}

// ---------------------------------------------------------------------------
// Kernel A2: W2 -> W2T (256x128), zero row at W2T[32768..32895], Wo -> WoT.
// ---------------------------------------------------------------------------
__global__ __launch_bounds__(1024) void transpose_kernel(
    const float* __restrict__ W2, const float* __restrict__ Wo,
    float* __restrict__ W2T, float* __restrict__ WoT) {
  const int idx = blockIdx.x * 1024 + threadIdx.x;
  if (idx < H2 * H1) {
    const int o = idx >> 8;
    const int j = idx & 255;
    W2T[j * H2 + o] = W2[idx];
  } else if (idx < H2 * H1 + H2) {
    W2T[idx] = 0.f;  // zero row (global dummy target)
  } else if (idx < H2 * H1 + H2 + NC * H2) {
    const int k = idx - (H2 * H1 + H2);
    const int o = k >> 7;
    const int j = k & 127;
    WoT[j * NC + o] = Wo[k];
  }
}

__device__ __forceinline__ int mbcnt64(unsigned long long m) {
  return (int)__builtin_amdgcn_mbcnt_hi(
      (unsigned)(m >> 32), __builtin_amdgcn_mbcnt_lo((unsigned)m, 0u));
}

// ---------------------------------------------------------------------------
// Kernel B: fused 20-step recurrent SNN. 256 persistent blocks (1/CU),
// 16 waves/block, 4 rows/wave.
// Spiking-row offsets are rank-compacted into per-wave LDS lists, split by
// row index: j<128 -> LDS list (rows staged in LDS), j>=128 -> global list
// (rows read from L1/L2-resident W2T on the vmcnt pipe). Global part: 16
// branchless always-issued loads (zero-row dummies, SGPR-selected offsets)
// issued BEFORE the LDS consume so L2 latency hides under it. Sum order:
// LDS part j ascending, global part j ascending, bias last -> bit-exact.
// ---------------------------------------------------------------------------
__global__ __launch_bounds__(1024) void snn_kernel(
    const float* __restrict__ cur1, const float* __restrict__ W2Tg,
    const float* __restrict__ WoTg, const float* __restrict__ b2,
    const float* __restrict__ bo, const int* __restrict__ nsp,
    float* __restrict__ out) {
  extern __shared__ float lds[];

  const int tid = threadIdx.x;
  {
    // stage W2T rows 0..127 (64 KB) + WoT (5 KB): straight coalesced copy
    float4* dst = (float4*)lds;
    const float4* src = (const float4*)W2Tg;
#pragma unroll
    for (int i = 0; i < 4; ++i) dst[tid + i * 1024] = src[tid + i * 1024];
    if (tid < 320)
      ((float4*)((char*)lds + WOT_OFF))[tid] = ((const float4*)WoTg)[tid];
  }
  __syncthreads();

  const int w = tid >> 6;
  const int l = tid & 63;
  const int lo = (l < NC) ? l : 0;
  const float bb0 = b2[2 * l];
  const float bb1 = b2[2 * l + 1];
  const float bol = bo[lo];
  const int nsteps = *nsp;

  int* scrL = (int*)((char*)lds + SCR_OFF) + w * 256;  // 128 ints
  int* scrG = scrL + 128;                              // 128 ints
  const char* w2b = (const char*)lds + 8 * l;          // LDS rows base
  const char* w2g = (const char*)W2Tg + 8 * l;         // global rows base
  const char* wob = (const char*)lds + WOT_OFF + 4 * lo;

  // per-lane constant byte offsets
  const int wr0 = l << 9;                // LDS row l
  const int wr1 = (64 + l) << 9;         // LDS row 64+l
  const int gr2 = (128 + l) << 9;        // global row 128+l (rel. W2Tg)
  const int gr3 = (192 + l) << 9;        // global row 192+l
  const int or0 = 80 * l;                // even output row 2l
  const int or1 = 80 * l + 40;           // odd output row 2l+1

#define LDS_B8()                                      \
  {                                                   \
    const int4 ia = *(const int4*)(scrL + k);         \
    const int4 ib = *(const int4*)(scrL + k + 4);     \
    const v2f p0 = *(const v2f*)(w2b + ia.x);         \
    const v2f p1 = *(const v2f*)(w2b + ia.y);         \
    const v2f p2 = *(const v2f*)(w2b + ia.z);         \
    const v2f p3 = *(const v2f*)(w2b + ia.w);         \
    const v2f p4 = *(const v2f*)(w2b + ib.x);         \
    const v2f p5 = *(const v2f*)(w2b + ib.y);         \
    const v2f p6 = *(const v2f*)(w2b + ib.z);         \
    const v2f p7 = *(const v2f*)(w2b + ib.w);         \
    acc += p0; acc += p1; acc += p2; acc += p3;       \
    acc += p4; acc += p5; acc += p6; acc += p7;       \
  }

#define OUT_B8()                                      \
  {                                                   \
    const int4 ia = *(const int4*)(scrL + k);         \
    const int4 ib = *(const int4*)(scrL + k + 4);     \
    const float q0 = *(const float*)(wob + ia.x);     \
    const float q1 = *(const float*)(wob + ia.y);     \
    const float q2 = *(const float*)(wob + ia.z);     \
    const float q3 = *(const float*)(wob + ia.w);     \
    const float q4 = *(const float*)(wob + ib.x);     \
    const float q5 = *(const float*)(wob + ib.y);     \
    const float q6 = *(const float*)(wob + ib.z);     \
    const float q7 = *(const float*)(wob + ib.w);     \
    co += q0; co += q1; co += q2; co += q3;           \
    co += q4; co += q5; co += q6; co += q7;           \
  }

// select slot offset: real list entry while i < SG, else global zero row
#define GSEL(reg, vec_comp, i)                                   \
  int reg = __builtin_amdgcn_readfirstlane(vec_comp);            \
  reg = (i < SG) ? reg : ZG;

  for (int r = 0; r < 4; ++r) {
    const long b = (long)blockIdx.x * 64 + w * 4 + r;

    float c[4];
#pragma unroll
    for (int i = 0; i < 4; ++i) c[i] = cur1[b * H1 + i * 64 + l];

    float m1[4] = {0.f, 0.f, 0.f, 0.f};
    float sp1[4] = {0.f, 0.f, 0.f, 0.f};
    float m2a = 0.f, m2b = 0.f, sp2a = 0.f, sp2b = 0.f;
    float mo = 0.f, spo = 0.f, cnt = 0.f;

    for (int t = 0; t < nsteps; ++t) {
      // ---- layer 1 LIF + spike masks ----
      float n0 = fmaf(0.5f, m1[0], c[0]) - sp1[0];
      float n1 = fmaf(0.5f, m1[1], c[1]) - sp1[1];
      float n2 = fmaf(0.5f, m1[2], c[2]) - sp1[2];
      float n3 = fmaf(0.5f, m1[3], c[3]) - sp1[3];
      const bool s0 = n0 > 1.0f;
      const bool s1 = n1 > 1.0f;
      const bool s2 = n2 > 1.0f;
      const bool s3 = n3 > 1.0f;
      m1[0] = n0; m1[1] = n1; m1[2] = n2; m1[3] = n3;
      sp1[0] = s0 ? 1.0f : 0.0f;
      sp1[1] = s1 ? 1.0f : 0.0f;
      sp1[2] = s2 ? 1.0f : 0.0f;
      sp1[3] = s3 ? 1.0f : 0.0f;
      const unsigned long long g0 = __ballot(s0);
      const unsigned long long g1 = __ballot(s1);
      const unsigned long long g2 = __ballot(s2);
      const unsigned long long g3 = __ballot(s3);
      const int pc0 = (int)__popcll(g0);
      const int pc1 = (int)__popcll(g1);
      const int pc2 = (int)__popcll(g2);
      const int pc3 = (int)__popcll(g3);
      const int SL = pc0 + pc1;
      const int SG = pc2 + pc3;

      // ---- build split offset lists (j-ascending within each) ----
      if (s0) scrL[mbcnt64(g0)] = wr0;
      if (s1) scrL[pc0 + mbcnt64(g1)] = wr1;
      if (s2) scrG[mbcnt64(g2)] = gr2;
      if (s3) scrG[pc2 + mbcnt64(g3)] = gr3;
      asm volatile("s_waitcnt lgkmcnt(0)" ::: "memory");

      // ---- GLOBAL part first: read idx, issue 16 branchless loads ----
      const int4 ga = *(const int4*)(scrG);
      const int4 gb = *(const int4*)(scrG + 4);
      const int4 gc = *(const int4*)(scrG + 8);
      const int4 gd = *(const int4*)(scrG + 12);
      GSEL(o0, ga.x, 0)  GSEL(o1, ga.y, 1)  GSEL(o2, ga.z, 2)  GSEL(o3, ga.w, 3)
      GSEL(o4, gb.x, 4)  GSEL(o5, gb.y, 5)  GSEL(o6, gb.z, 6)  GSEL(o7, gb.w, 7)
      GSEL(o8, gc.x, 8)  GSEL(o9, gc.y, 9)  GSEL(o10, gc.z, 10) GSEL(o11, gc.w, 11)
      GSEL(o12, gd.x, 12) GSEL(o13, gd.y, 13) GSEL(o14, gd.z, 14) GSEL(o15, gd.w, 15)
      const v2f q0 = *(const v2f*)(w2g + o0);
      const v2f q1 = *(const v2f*)(w2g + o1);
      const v2f q2 = *(const v2f*)(w2g + o2);
      const v2f q3 = *(const v2f*)(w2g + o3);
      const v2f q4 = *(const v2f*)(w2g + o4);
      const v2f q5 = *(const v2f*)(w2g + o5);
      const v2f q6 = *(const v2f*)(w2g + o6);
      const v2f q7 = *(const v2f*)(w2g + o7);
      const v2f q8 = *(const v2f*)(w2g + o8);
      const v2f q9 = *(const v2f*)(w2g + o9);
      const v2f q10 = *(const v2f*)(w2g + o10);
      const v2f q11 = *(const v2f*)(w2g + o11);
      const v2f q12 = *(const v2f*)(w2g + o12);
      const v2f q13 = *(const v2f*)(w2g + o13);
      const v2f q14 = *(const v2f*)(w2g + o14);
      const v2f q15 = *(const v2f*)(w2g + o15);

      // ---- LDS part: exact-size clustered batches (j<128, ascending) ----
      v2f acc = {0.f, 0.f};
      int k = 0;
      for (; k + 8 <= SL; k += 8) LDS_B8();
      if (SL & 4) {
        const int4 ia = *(const int4*)(scrL + k);
        const v2f p0 = *(const v2f*)(w2b + ia.x);
        const v2f p1 = *(const v2f*)(w2b + ia.y);
        const v2f p2 = *(const v2f*)(w2b + ia.z);
        const v2f p3 = *(const v2f*)(w2b + ia.w);
        acc += p0; acc += p1; acc += p2; acc += p3;
        k += 4;
      }
      if (SL & 2) {
        const int2 ia = *(const int2*)(scrL + k);
        const v2f p0 = *(const v2f*)(w2b + ia.x);
        const v2f p1 = *(const v2f*)(w2b + ia.y);
        acc += p0; acc += p1;
        k += 2;
      }
      if (SL & 1) {
        const v2f p0 = *(const v2f*)(w2b + scrL[k]);
        acc += p0;
      }

      // ---- append global part in order (dummies add +0.0f, exact) ----
      acc += q0;  acc += q1;  acc += q2;  acc += q3;
      acc += q4;  acc += q5;  acc += q6;  acc += q7;
      acc += q8;  acc += q9;  acc += q10; acc += q11;
      acc += q12; acc += q13; acc += q14; acc += q15;
      for (int k2 = 16; k2 < SG; ++k2) {  // rare tail (>16 upper spikes)
        const int o = __builtin_amdgcn_readfirstlane(scrG[k2]);
        const v2f qq = *(const v2f*)(w2g + o);
        acc += qq;
      }
      const float a0 = acc.x + bb0;
      const float a1 = acc.y + bb1;

      // ---- layer 2 LIF ----
      m2a = fmaf(0.5f, m2a, a0) - sp2a;
      m2b = fmaf(0.5f, m2b, a1) - sp2b;
      const bool sa = m2a > 1.0f;
      const bool sb = m2b > 1.0f;
      const unsigned long long mA = __ballot(sa);
      const unsigned long long mB = __ballot(sb);
      sp2a = sa ? 1.0f : 0.0f;
      sp2b = sb ? 1.0f : 0.0f;
      const int pcA = (int)__popcll(mA);
      const int So = pcA + (int)__popcll(mB);

      // ---- output-layer list (evens ascending, then odds) ----
      if (sa) scrL[mbcnt64(mA)] = or0;
      if (sb) scrL[pcA + mbcnt64(mB)] = or1;
      asm volatile("s_waitcnt lgkmcnt(0)" ::: "memory");

      float co = 0.f;
      k = 0;
      for (; k + 8 <= So; k += 8) OUT_B8();
      if (So & 4) {
        const int4 ia = *(const int4*)(scrL + k);
        const float u0 = *(const float*)(wob + ia.x);
        const float u1 = *(const float*)(wob + ia.y);
        const float u2 = *(const float*)(wob + ia.z);
        const float u3 = *(const float*)(wob + ia.w);
        co += u0; co += u1; co += u2; co += u3;
        k += 4;
      }
      if (So & 2) {
        const int2 ia = *(const int2*)(scrL + k);
        const float u0 = *(const float*)(wob + ia.x);
        const float u1 = *(const float*)(wob + ia.y);
        co += u0; co += u1;
        k += 2;
      }
      if (So & 1) {
        co += *(const float*)(wob + scrL[k]);
      }
      co += bol;

      // ---- output LIF + spike count ----
      mo = fmaf(0.5f, mo, co) - spo;
      const bool so = mo > 1.0f;
      spo = so ? 1.0f : 0.0f;
      cnt += spo;
    }

    if (l < NC) out[b * NC + l] = cnt;
  }
#undef LDS_B8
#undef OUT_B8
#undef GSEL
}

// ---------------------------------------------------------------------------
extern "C" void kernel_launch(void* const* d_in, const int* in_sizes, int n_in,
                              void* d_out, int out_size, void* d_ws,
                              size_t ws_size, hipStream_t stream) {
  const float* x  = (const float*)d_in[0];
  const float* W1 = (const float*)d_in[1];
  const float* b1 = (const float*)d_in[2];
  const float* W2 = (const float*)d_in[3];
  const float* b2 = (const float*)d_in[4];
  const float* Wo = (const float*)d_in[5];
  const float* bo = (const float*)d_in[6];
  const int* nsp  = (const int*)d_in[7];
  float* outp = (float*)d_out;

  // ws layout: cur1 (16384*256) | W2T (32768) + zero row (128) | WoT (1280)
  float* cur1 = (float*)d_ws;
  float* W2Tg = cur1 + (size_t)B_TOT * H1;
  float* WoTg = W2Tg + H1 * H2 + H2;

  gemm1_kernel<<<B_TOT / 16, 256, 0, stream>>>(x, W1, b1, cur1);
  transpose_kernel<<<(H2 * H1 + H2 + NC * H2 + 1023) / 1024, 1024, 0,
                     stream>>>(W2, Wo, W2Tg, WoTg);

  hipFuncSetAttribute((const void*)snn_kernel,
                      hipFuncAttributeMaxDynamicSharedMemorySize, LDS_BYTES);
  snn_kernel<<<256, 1024, LDS_BYTES, stream>>>(cur1, W2Tg, WoTg, b2, bo, nsp,
                                               outp);
}

// Round 9
// 139.979 us; speedup vs baseline: 1.5007x; 1.5007x over previous
//
#include <hip/hip_runtime.h>
#include <stdint.h>

#define B_TOT 16384
#define IN_DIM 128
#define H1 256
#define H2 128
#define NC 10

// LDS byte layout: W2T [256][128] f32 | WoT [128][10] f32
#define W2T_BYTES (H1 * H2 * 4)            // 131072
#define WOT_OFF   W2T_BYTES
#define WOT_BYTES (H2 * NC * 4)            // 5120
#define LDS_BYTES (WOT_OFF + WOT_BYTES)    // 136192

typedef float v2f __attribute__((ext_vector_type(2)));

// ---------------------------------------------------------------------------
// Kernel A: cur1[b][n] = sum_k x[b][k]*W1[n][k] + b1[n]   (r2 version)
// ---------------------------------------------------------------------------
__global__ __launch_bounds__(256) void gemm1_kernel(
    const float* __restrict__ x, const float* __restrict__ W1,
    const float* __restrict__ b1, float* __restrict__ cur1) {
  __shared__ float xs[16 * 128];
  const int tid = threadIdx.x;
  const long row0 = (long)blockIdx.x * 16;

  const float4* xt = (const float4*)(x + row0 * IN_DIM);
  float4* xs4 = (float4*)xs;
  xs4[tid] = xt[tid];
  xs4[tid + 256] = xt[tid + 256];
  __syncthreads();

  const int n = tid;
  float acc[16];
#pragma unroll
  for (int r = 0; r < 16; ++r) acc[r] = 0.f;

  const float* wrow = W1 + n * IN_DIM;
  for (int k0 = 0; k0 < IN_DIM; k0 += 4) {
    const float4 wv = *(const float4*)(wrow + k0);
#pragma unroll
    for (int r = 0; r < 16; ++r) {
      const float4 xv = *(const float4*)(xs + r * IN_DIM + k0);
      acc[r] = fmaf(wv.x, xv.x, acc[r]);
      acc[r] = fmaf(wv.y, xv.y, acc[r]);
      acc[r] = fmaf(wv.z, xv.z, acc[r]);
      acc[r] = fmaf(wv.w, xv.w, acc[r]);
    }
  }
  const float bias = b1[n];
#pragma unroll
  for (int r = 0; r < 16; ++r)
    cur1[(row0 + r) * H1 + n] = acc[r] + bias;
}

// ---------------------------------------------------------------------------
// Kernel A2: W2 -> W2T (256x128), Wo -> WoT into workspace.
// ---------------------------------------------------------------------------
__global__ __launch_bounds__(1024) void transpose_kernel(
    const float* __restrict__ W2, const float* __restrict__ Wo,
    float* __restrict__ W2T, float* __restrict__ WoT) {
  const int idx = blockIdx.x * 1024 + threadIdx.x;
  if (idx < H2 * H1) {
    const int o = idx >> 8;
    const int j = idx & 255;
    W2T[j * H2 + o] = W2[idx];
  } else {
    const int k = idx - H2 * H1;
    if (k < NC * H2) {
      const int o = k >> 7;
      const int j = k & 127;
      WoT[j * NC + o] = Wo[k];
    }
  }
}

// ---------------------------------------------------------------------------
// Kernel B: fused 20-step recurrent SNN. 256 persistent blocks (1/CU),
// 16 waves/block, 4 rows/wave. Full W2T (128 KB) + WoT (5 KB) in LDS.
// Spike extraction is PURE SALU on the wave-uniform ballot masks
// (s_ff1 + m&=m-1); per group, 8 offsets are extracted ahead, then 8
// ds_read_b64 issue back-to-back (1 v_add each), then 8 ordered adds.
// No index list, no ds_writes, no lgkmcnt barriers — the only LDS
// traffic is the weight payload itself. Addend order: groups i=0..3
// ascending, j ascending within group, bias last; output layer evens
// then odds -> bit-identical to the verified r2 summation.
// ---------------------------------------------------------------------------
__global__ __launch_bounds__(1024) void snn_kernel(
    const float* __restrict__ cur1, const float* __restrict__ W2Tg,
    const float* __restrict__ WoTg, const float* __restrict__ b2,
    const float* __restrict__ bo, const int* __restrict__ nsp,
    float* __restrict__ out) {
  extern __shared__ float lds[];

  const int tid = threadIdx.x;
  {
    // stage W2T (128 KB) + WoT (5 KB): straight coalesced float4 copy
    float4* dst = (float4*)lds;
    const float4* src = (const float4*)W2Tg;
#pragma unroll
    for (int i = 0; i < 8; ++i) dst[tid + i * 1024] = src[tid + i * 1024];
    if (tid < 320)
      ((float4*)((char*)lds + WOT_OFF))[tid] = ((const float4*)WoTg)[tid];
  }
  __syncthreads();

  const int w = tid >> 6;
  const int l = tid & 63;
  const int lo = (l < NC) ? l : 0;
  const float bb0 = b2[2 * l];
  const float bb1 = b2[2 * l + 1];
  const float bol = bo[lo];
  const int nsteps = *nsp;

  const char* w2p = (const char*)lds + 8 * l;            // lane pair base
  const char* wop = (const char*)lds + WOT_OFF + 4 * lo; // lane out base

// extract lowest spike: offset = j*512 bytes; pure SALU on uniform mask
#define EX(m) __extension__({                       \
    const int _j = (int)__builtin_ctzll(m);         \
    (m) &= (m) - 1;                                 \
    _j << 9;                                        \
  })
// output-layer extract: neuron 2j (+oo selects odd), row stride 40 B
#define EXO(m, oo) __extension__({                  \
    const int _j = (int)__builtin_ctzll(m);         \
    (m) &= (m) - 1;                                 \
    _j * 80 + (oo);                                 \
  })

#define GRP(mrg, GOFF)                                            \
  {                                                               \
    unsigned long long m = (mrg);                                 \
    if (m) {                                                      \
      const int Si = (int)__popcll(m);                            \
      const char* bp = w2p + (GOFF);                              \
      int k = 0;                                                  \
      for (; k + 8 <= Si; k += 8) {                               \
        const int o0 = EX(m); const int o1 = EX(m);               \
        const int o2 = EX(m); const int o3 = EX(m);               \
        const int o4 = EX(m); const int o5 = EX(m);               \
        const int o6 = EX(m); const int o7 = EX(m);               \
        const v2f p0 = *(const v2f*)(bp + o0);                    \
        const v2f p1 = *(const v2f*)(bp + o1);                    \
        const v2f p2 = *(const v2f*)(bp + o2);                    \
        const v2f p3 = *(const v2f*)(bp + o3);                    \
        const v2f p4 = *(const v2f*)(bp + o4);                    \
        const v2f p5 = *(const v2f*)(bp + o5);                    \
        const v2f p6 = *(const v2f*)(bp + o6);                    \
        const v2f p7 = *(const v2f*)(bp + o7);                    \
        acc += p0; acc += p1; acc += p2; acc += p3;               \
        acc += p4; acc += p5; acc += p6; acc += p7;               \
      }                                                           \
      if (Si & 4) {                                               \
        const int o0 = EX(m); const int o1 = EX(m);               \
        const int o2 = EX(m); const int o3 = EX(m);               \
        const v2f p0 = *(const v2f*)(bp + o0);                    \
        const v2f p1 = *(const v2f*)(bp + o1);                    \
        const v2f p2 = *(const v2f*)(bp + o2);                    \
        const v2f p3 = *(const v2f*)(bp + o3);                    \
        acc += p0; acc += p1; acc += p2; acc += p3;               \
      }                                                           \
      if (Si & 2) {                                               \
        const int o0 = EX(m); const int o1 = EX(m);               \
        const v2f p0 = *(const v2f*)(bp + o0);                    \
        const v2f p1 = *(const v2f*)(bp + o1);                    \
        acc += p0; acc += p1;                                     \
      }                                                           \
      if (Si & 1) {                                               \
        const int o0 = EX(m);                                     \
        const v2f p0 = *(const v2f*)(bp + o0);                    \
        acc += p0;                                                \
      }                                                           \
    }                                                             \
  }

#define OGRP(mrg, oo)                                             \
  {                                                               \
    unsigned long long m = (mrg);                                 \
    if (m) {                                                      \
      const int Si = (int)__popcll(m);                            \
      int k = 0;                                                  \
      for (; k + 4 <= Si; k += 4) {                               \
        const int o0 = EXO(m, oo); const int o1 = EXO(m, oo);     \
        const int o2 = EXO(m, oo); const int o3 = EXO(m, oo);     \
        const float q0 = *(const float*)(wop + o0);               \
        const float q1 = *(const float*)(wop + o1);               \
        const float q2 = *(const float*)(wop + o2);               \
        const float q3 = *(const float*)(wop + o3);               \
        co += q0; co += q1; co += q2; co += q3;                   \
      }                                                           \
      if (Si & 2) {                                               \
        const int o0 = EXO(m, oo); const int o1 = EXO(m, oo);     \
        const float q0 = *(const float*)(wop + o0);               \
        const float q1 = *(const float*)(wop + o1);               \
        co += q0; co += q1;                                       \
      }                                                           \
      if (Si & 1) {                                               \
        const int o0 = EXO(m, oo);                                \
        const float q0 = *(const float*)(wop + o0);               \
        co += q0;                                                 \
      }                                                           \
    }                                                             \
  }

  for (int r = 0; r < 4; ++r) {
    const long b = (long)blockIdx.x * 64 + w * 4 + r;

    float c[4];
#pragma unroll
    for (int i = 0; i < 4; ++i) c[i] = cur1[b * H1 + i * 64 + l];

    float m1[4] = {0.f, 0.f, 0.f, 0.f};
    float sp1[4] = {0.f, 0.f, 0.f, 0.f};
    float m2a = 0.f, m2b = 0.f, sp2a = 0.f, sp2b = 0.f;
    float mo = 0.f, spo = 0.f, cnt = 0.f;

    for (int t = 0; t < nsteps; ++t) {
      // ---- layer 1 LIF + spike masks ----
      float n0 = fmaf(0.5f, m1[0], c[0]) - sp1[0];
      float n1 = fmaf(0.5f, m1[1], c[1]) - sp1[1];
      float n2 = fmaf(0.5f, m1[2], c[2]) - sp1[2];
      float n3 = fmaf(0.5f, m1[3], c[3]) - sp1[3];
      const bool s0 = n0 > 1.0f;
      const bool s1 = n1 > 1.0f;
      const bool s2 = n2 > 1.0f;
      const bool s3 = n3 > 1.0f;
      m1[0] = n0; m1[1] = n1; m1[2] = n2; m1[3] = n3;
      sp1[0] = s0 ? 1.0f : 0.0f;
      sp1[1] = s1 ? 1.0f : 0.0f;
      sp1[2] = s2 ? 1.0f : 0.0f;
      sp1[3] = s3 ? 1.0f : 0.0f;
      const unsigned long long g0 = __ballot(s0);
      const unsigned long long g1 = __ballot(s1);
      const unsigned long long g2 = __ballot(s2);
      const unsigned long long g3 = __ballot(s3);

      // ---- cur2 = s1 @ W2^T (+ b2): SALU-extracted clustered batches ----
      v2f acc = {0.f, 0.f};
      GRP(g0, 0)
      GRP(g1, 65536 / 2)      // 64*512  = 32768
      GRP(g2, 65536)          // 128*512 = 65536
      GRP(g3, 65536 + 32768)  // 192*512 = 98304
      const float a0 = acc.x + bb0;
      const float a1 = acc.y + bb1;

      // ---- layer 2 LIF ----
      m2a = fmaf(0.5f, m2a, a0) - sp2a;
      m2b = fmaf(0.5f, m2b, a1) - sp2b;
      const bool sa = m2a > 1.0f;
      const bool sb = m2b > 1.0f;
      const unsigned long long mA = __ballot(sa);
      const unsigned long long mB = __ballot(sb);
      sp2a = sa ? 1.0f : 0.0f;
      sp2b = sb ? 1.0f : 0.0f;

      // ---- output layer: evens ascending, then odds ----
      float co = 0.f;
      OGRP(mA, 0)
      OGRP(mB, 40)
      co += bol;

      // ---- output LIF + spike count ----
      mo = fmaf(0.5f, mo, co) - spo;
      const bool so = mo > 1.0f;
      spo = so ? 1.0f : 0.0f;
      cnt += spo;
    }

    if (l < NC) out[b * NC + l] = cnt;
  }
#undef EX
#undef EXO
#undef GRP
#undef OGRP
}

// ---------------------------------------------------------------------------
extern "C" void kernel_launch(void* const* d_in, const int* in_sizes, int n_in,
                              void* d_out, int out_size, void* d_ws,
                              size_t ws_size, hipStream_t stream) {
  const float* x  = (const float*)d_in[0];
  const float* W1 = (const float*)d_in[1];
  const float* b1 = (const float*)d_in[2];
  const float* W2 = (const float*)d_in[3];
  const float* b2 = (const float*)d_in[4];
  const float* Wo = (const float*)d_in[5];
  const float* bo = (const float*)d_in[6];
  const int* nsp  = (const int*)d_in[7];
  float* outp = (float*)d_out;

  // ws layout: cur1 (16384*256 f) | W2T (32768 f) | WoT (1280 f)
  float* cur1 = (float*)d_ws;
  float* W2Tg = cur1 + (size_t)B_TOT * H1;
  float* WoTg = W2Tg + H1 * H2;

  gemm1_kernel<<<B_TOT / 16, 256, 0, stream>>>(x, W1, b1, cur1);
  transpose_kernel<<<(H2 * H1 + NC * H2 + 1023) / 1024, 1024, 0, stream>>>(
      W2, Wo, W2Tg, WoTg);

  hipFuncSetAttribute((const void*)snn_kernel,
                      hipFuncAttributeMaxDynamicSharedMemorySize, LDS_BYTES);
  snn_kernel<<<256, 1024, LDS_BYTES, stream>>>(cur1, W2Tg, WoTg, b2, bo, nsp,
                                               outp);
}

// Round 10
// 137.456 us; speedup vs baseline: 1.5282x; 1.0184x over previous
//
#include <hip/hip_runtime.h>
#include <stdint.h>

#define B_TOT 16384
#define IN_DIM 128
#define H1 256
#define H2 128
#define NC 10

// LDS byte layout:
//   W2T rows 0..255 [256][128] f32 + zero row 256       (131584 B)
//   WoT  rows 0..127 [128][10] f32 + zero row 128       (5160 B)
//   per-wave u16 index lists: 16 waves x 1 KB           (16384 B)
#define W2T_BYTES (257 * H2 * 4)             // 131584
#define WOT_OFF   W2T_BYTES
#define SCR_OFF   136768                     // WOT_OFF + 5160, aligned
#define LDS_BYTES (SCR_OFF + 16 * 1024)      // 153152

#define JDUMMY 256   // main dummy index -> W2T zero row (byte 131072)
#define ODUMMY 128   // out  dummy index -> WoT zero row (byte 5120 rel WoT)

typedef float v2f __attribute__((ext_vector_type(2)));

// ---------------------------------------------------------------------------
// Kernel A: cur1[b][n] = sum_k x[b][k]*W1[n][k] + b1[n]   (r2 version)
// ---------------------------------------------------------------------------
__global__ __launch_bounds__(256) void gemm1_kernel(
    const float* __restrict__ x, const float* __restrict__ W1,
    const float* __restrict__ b1, float* __restrict__ cur1) {
  __shared__ float xs[16 * 128];
  const int tid = threadIdx.x;
  const long row0 = (long)blockIdx.x * 16;

  const float4* xt = (const float4*)(x + row0 * IN_DIM);
  float4* xs4 = (float4*)xs;
  xs4[tid] = xt[tid];
  xs4[tid + 256] = xt[tid + 256];
  __syncthreads();

  const int n = tid;
  float acc[16];
#pragma unroll
  for (int r = 0; r < 16; ++r) acc[r] = 0.f;

  const float* wrow = W1 + n * IN_DIM;
  for (int k0 = 0; k0 < IN_DIM; k0 += 4) {
    const float4 wv = *(const float4*)(wrow + k0);
#pragma unroll
    for (int r = 0; r < 16; ++r) {
      const float4 xv = *(const float4*)(xs + r * IN_DIM + k0);
      acc[r] = fmaf(wv.x, xv.x, acc[r]);
      acc[r] = fmaf(wv.y, xv.y, acc[r]);
      acc[r] = fmaf(wv.z, xv.z, acc[r]);
      acc[r] = fmaf(wv.w, xv.w, acc[r]);
    }
  }
  const float bias = b1[n];
#pragma unroll
  for (int r = 0; r < 16; ++r)
    cur1[(row0 + r) * H1 + n] = acc[r] + bias;
}

// ---------------------------------------------------------------------------
// Kernel A2: W2 -> W2T (256x128), Wo -> WoT into workspace.
// ---------------------------------------------------------------------------
__global__ __launch_bounds__(1024) void transpose_kernel(
    const float* __restrict__ W2, const float* __restrict__ Wo,
    float* __restrict__ W2T, float* __restrict__ WoT) {
  const int idx = blockIdx.x * 1024 + threadIdx.x;
  if (idx < H2 * H1) {
    const int o = idx >> 8;
    const int j = idx & 255;
    W2T[j * H2 + o] = W2[idx];
  } else {
    const int k = idx - H2 * H1;
    if (k < NC * H2) {
      const int o = k >> 7;
      const int j = k & 127;
      WoT[j * NC + o] = Wo[k];
    }
  }
}

__device__ __forceinline__ int mbcnt64(unsigned long long m) {
  return (int)__builtin_amdgcn_mbcnt_hi(
      (unsigned)(m >> 32), __builtin_amdgcn_mbcnt_lo((unsigned)m, 0u));
}

// ---------------------------------------------------------------------------
// Kernel B: fused 20-step recurrent SNN. 256 persistent blocks (1/CU),
// 16 waves/block, 4 rows/wave processed as TWO interleaved pairs.
// Per t-step: both rows' spiking-row indices are rank-compacted into
// per-wave u16 LDS lists (j-ascending = reference order), padded to a
// multiple of 8 with zero-row dummies (+0.0f, exact). Consume is a
// uniform stream of 8-wide ds_read_b64 clusters, A/B interleaved so each
// row's LDS latency hides under the other's issue+adds. Output layer
// (evens then odds) gets the same treatment with 8-wide f32 clusters.
// Addend order per row is bit-identical to the verified r2 kernel.
// ---------------------------------------------------------------------------
__global__ __launch_bounds__(1024) void snn_kernel(
    const float* __restrict__ cur1, const float* __restrict__ W2Tg,
    const float* __restrict__ WoTg, const float* __restrict__ b2,
    const float* __restrict__ bo, const int* __restrict__ nsp,
    float* __restrict__ out) {
  extern __shared__ float lds[];

  const int tid = threadIdx.x;
  {
    // stage W2T (128 KB) + WoT (5 KB): straight coalesced float4 copy
    float4* dst = (float4*)lds;
    const float4* src = (const float4*)W2Tg;
#pragma unroll
    for (int i = 0; i < 8; ++i) dst[tid + i * 1024] = src[tid + i * 1024];
    if (tid < 320)
      ((float4*)((char*)lds + WOT_OFF))[tid] = ((const float4*)WoTg)[tid];
    // zero rows (dummy targets)
    if (tid < 32)
      ((float4*)((char*)lds))[256 * 32 + tid] = make_float4(0.f, 0.f, 0.f, 0.f);
    if (tid < NC) ((float*)((char*)lds + WOT_OFF))[128 * NC + tid] = 0.f;
  }
  __syncthreads();

  const int w = tid >> 6;
  const int l = tid & 63;
  const int lo = (l < NC) ? l : 0;
  const float bb0 = b2[2 * l];
  const float bb1 = b2[2 * l + 1];
  const float bol = bo[lo];
  const int nsteps = *nsp;

  unsigned short* scrA = (unsigned short*)((char*)lds + SCR_OFF) + w * 512;
  unsigned short* scrB = scrA + 256;
  const char* w2p = (const char*)lds + 8 * l;             // lane pair base
  const char* wop = (const char*)lds + WOT_OFF + 4 * lo;  // lane out base

// ---- 8-wide main cluster: list read (broadcast b128) -> 8 ds_read_b64 ----
#define LOAD8(P, scrp, kidx)                                              \
  const int4 P##i = *(const int4*)((const char*)(scrp) + (kidx) * 16);    \
  const int P##j0 = P##i.x & 0xffff;                                      \
  const int P##j1 = ((unsigned)P##i.x) >> 16;                             \
  const int P##j2 = P##i.y & 0xffff;                                      \
  const int P##j3 = ((unsigned)P##i.y) >> 16;                             \
  const int P##j4 = P##i.z & 0xffff;                                      \
  const int P##j5 = ((unsigned)P##i.z) >> 16;                             \
  const int P##j6 = P##i.w & 0xffff;                                      \
  const int P##j7 = ((unsigned)P##i.w) >> 16;                             \
  const v2f P##p0 = *(const v2f*)(w2p + (P##j0 << 9));                    \
  const v2f P##p1 = *(const v2f*)(w2p + (P##j1 << 9));                    \
  const v2f P##p2 = *(const v2f*)(w2p + (P##j2 << 9));                    \
  const v2f P##p3 = *(const v2f*)(w2p + (P##j3 << 9));                    \
  const v2f P##p4 = *(const v2f*)(w2p + (P##j4 << 9));                    \
  const v2f P##p5 = *(const v2f*)(w2p + (P##j5 << 9));                    \
  const v2f P##p6 = *(const v2f*)(w2p + (P##j6 << 9));                    \
  const v2f P##p7 = *(const v2f*)(w2p + (P##j7 << 9));

#define ADD8(P, acc)                                                      \
  acc += P##p0; acc += P##p1; acc += P##p2; acc += P##p3;                 \
  acc += P##p4; acc += P##p5; acc += P##p6; acc += P##p7;

// ---- 8-wide output cluster: idx -> offset idx*40, f32 reads ----
#define OLOAD8(P, scrp, kidx)                                             \
  const int4 P##i = *(const int4*)((const char*)(scrp) + (kidx) * 16);    \
  const int P##j0 = P##i.x & 0xffff;                                      \
  const int P##j1 = ((unsigned)P##i.x) >> 16;                             \
  const int P##j2 = P##i.y & 0xffff;                                      \
  const int P##j3 = ((unsigned)P##i.y) >> 16;                             \
  const int P##j4 = P##i.z & 0xffff;                                      \
  const int P##j5 = ((unsigned)P##i.z) >> 16;                             \
  const int P##j6 = P##i.w & 0xffff;                                      \
  const int P##j7 = ((unsigned)P##i.w) >> 16;                             \
  const float P##q0 = *(const float*)(wop + P##j0 * 40);                  \
  const float P##q1 = *(const float*)(wop + P##j1 * 40);                  \
  const float P##q2 = *(const float*)(wop + P##j2 * 40);                  \
  const float P##q3 = *(const float*)(wop + P##j3 * 40);                  \
  const float P##q4 = *(const float*)(wop + P##j4 * 40);                  \
  const float P##q5 = *(const float*)(wop + P##j5 * 40);                  \
  const float P##q6 = *(const float*)(wop + P##j6 * 40);                  \
  const float P##q7 = *(const float*)(wop + P##j7 * 40);

#define OADD8(P, co)                                                      \
  co += P##q0; co += P##q1; co += P##q2; co += P##q3;                     \
  co += P##q4; co += P##q5; co += P##q6; co += P##q7;

  for (int rp = 0; rp < 2; ++rp) {
    const long bA = (long)blockIdx.x * 64 + w * 4 + rp * 2;
    const long bB = bA + 1;

    float cA[4], cB[4];
#pragma unroll
    for (int i = 0; i < 4; ++i) {
      cA[i] = cur1[bA * H1 + i * 64 + l];
      cB[i] = cur1[bB * H1 + i * 64 + l];
    }

    float mA1[4] = {0.f, 0.f, 0.f, 0.f}, spA1[4] = {0.f, 0.f, 0.f, 0.f};
    float mB1[4] = {0.f, 0.f, 0.f, 0.f}, spB1[4] = {0.f, 0.f, 0.f, 0.f};
    float mA2a = 0.f, mA2b = 0.f, spA2a = 0.f, spA2b = 0.f;
    float mB2a = 0.f, mB2b = 0.f, spB2a = 0.f, spB2b = 0.f;
    float moA = 0.f, spoA = 0.f, cntA = 0.f;
    float moB = 0.f, spoB = 0.f, cntB = 0.f;

    for (int t = 0; t < nsteps; ++t) {
      // ---- layer 1 LIF + spike masks, both rows ----
      unsigned long long gA[4], gB[4];
      bool sA[4], sB[4];
#pragma unroll
      for (int i = 0; i < 4; ++i) {
        mA1[i] = fmaf(0.5f, mA1[i], cA[i]) - spA1[i];
        sA[i] = mA1[i] > 1.0f;
        spA1[i] = sA[i] ? 1.0f : 0.0f;
        gA[i] = __ballot(sA[i]);
        mB1[i] = fmaf(0.5f, mB1[i], cB[i]) - spB1[i];
        sB[i] = mB1[i] > 1.0f;
        spB1[i] = sB[i] ? 1.0f : 0.0f;
        gB[i] = __ballot(sB[i]);
      }
      const int pA0 = (int)__popcll(gA[0]);
      const int pA01 = pA0 + (int)__popcll(gA[1]);
      const int pA012 = pA01 + (int)__popcll(gA[2]);
      const int SA = pA012 + (int)__popcll(gA[3]);
      const int pB0 = (int)__popcll(gB[0]);
      const int pB01 = pB0 + (int)__popcll(gB[1]);
      const int pB012 = pB01 + (int)__popcll(gB[2]);
      const int SB = pB012 + (int)__popcll(gB[3]);

      // ---- build both index lists (rank-compacted, j-ascending) ----
      if (sA[0]) scrA[mbcnt64(gA[0])] = (unsigned short)l;
      if (sA[1]) scrA[pA0 + mbcnt64(gA[1])] = (unsigned short)(64 + l);
      if (sA[2]) scrA[pA01 + mbcnt64(gA[2])] = (unsigned short)(128 + l);
      if (sA[3]) scrA[pA012 + mbcnt64(gA[3])] = (unsigned short)(192 + l);
      if (sB[0]) scrB[mbcnt64(gB[0])] = (unsigned short)l;
      if (sB[1]) scrB[pB0 + mbcnt64(gB[1])] = (unsigned short)(64 + l);
      if (sB[2]) scrB[pB01 + mbcnt64(gB[2])] = (unsigned short)(128 + l);
      if (sB[3]) scrB[pB012 + mbcnt64(gB[3])] = (unsigned short)(192 + l);
      // pad each list to a multiple of 8 with zero-row dummies
      const int padA = (8 - (SA & 7)) & 7;
      const int padB = (8 - (SB & 7)) & 7;
      if (l < padA) scrA[SA + l] = JDUMMY;
      if (l < padB) scrB[SB + l] = JDUMMY;
      asm volatile("s_waitcnt lgkmcnt(0)" ::: "memory");

      // ---- cur2 = s1 @ W2^T (+ b2): interleaved 8-wide clusters ----
      v2f accA = {0.f, 0.f}, accB = {0.f, 0.f};
      {
        const int nA = (SA + 7) >> 3;
        const int nB = (SB + 7) >> 3;
        int ka = 0, kb = 0;
        while (ka < nA && kb < nB) {
          LOAD8(a_, scrA, ka)
          LOAD8(b_, scrB, kb)
          ADD8(a_, accA)
          ADD8(b_, accB)
          ++ka;
          ++kb;
        }
        while (ka < nA) {
          LOAD8(c_, scrA, ka)
          ADD8(c_, accA)
          ++ka;
        }
        while (kb < nB) {
          LOAD8(d_, scrB, kb)
          ADD8(d_, accB)
          ++kb;
        }
      }
      const float aA0 = accA.x + bb0;
      const float aA1 = accA.y + bb1;
      const float aB0 = accB.x + bb0;
      const float aB1 = accB.y + bb1;

      // ---- layer 2 LIF, both rows ----
      mA2a = fmaf(0.5f, mA2a, aA0) - spA2a;
      mA2b = fmaf(0.5f, mA2b, aA1) - spA2b;
      mB2a = fmaf(0.5f, mB2a, aB0) - spB2a;
      mB2b = fmaf(0.5f, mB2b, aB1) - spB2b;
      const bool saA = mA2a > 1.0f, sbA = mA2b > 1.0f;
      const bool saB = mB2a > 1.0f, sbB = mB2b > 1.0f;
      const unsigned long long mAe = __ballot(saA);
      const unsigned long long mAo = __ballot(sbA);
      const unsigned long long mBe = __ballot(saB);
      const unsigned long long mBo = __ballot(sbB);
      spA2a = saA ? 1.0f : 0.0f;
      spA2b = sbA ? 1.0f : 0.0f;
      spB2a = saB ? 1.0f : 0.0f;
      spB2b = sbB ? 1.0f : 0.0f;
      const int pAe = (int)__popcll(mAe);
      const int SoA = pAe + (int)__popcll(mAo);
      const int pBe = (int)__popcll(mBe);
      const int SoB = pBe + (int)__popcll(mBo);

      // ---- output-layer lists (evens ascending, then odds) ----
      if (saA) scrA[mbcnt64(mAe)] = (unsigned short)(2 * l);
      if (sbA) scrA[pAe + mbcnt64(mAo)] = (unsigned short)(2 * l + 1);
      if (saB) scrB[mbcnt64(mBe)] = (unsigned short)(2 * l);
      if (sbB) scrB[pBe + mbcnt64(mBo)] = (unsigned short)(2 * l + 1);
      const int padOA = (8 - (SoA & 7)) & 7;
      const int padOB = (8 - (SoB & 7)) & 7;
      if (l < padOA) scrA[SoA + l] = ODUMMY;
      if (l < padOB) scrB[SoB + l] = ODUMMY;
      asm volatile("s_waitcnt lgkmcnt(0)" ::: "memory");

      float coA = 0.f, coB = 0.f;
      {
        const int nA = (SoA + 7) >> 3;
        const int nB = (SoB + 7) >> 3;
        int ka = 0, kb = 0;
        while (ka < nA && kb < nB) {
          OLOAD8(e_, scrA, ka)
          OLOAD8(f_, scrB, kb)
          OADD8(e_, coA)
          OADD8(f_, coB)
          ++ka;
          ++kb;
        }
        while (ka < nA) {
          OLOAD8(g_, scrA, ka)
          OADD8(g_, coA)
          ++ka;
        }
        while (kb < nB) {
          OLOAD8(h_, scrB, kb)
          OADD8(h_, coB)
          ++kb;
        }
      }
      coA += bol;
      coB += bol;

      // ---- output LIF + spike count, both rows ----
      moA = fmaf(0.5f, moA, coA) - spoA;
      moB = fmaf(0.5f, moB, coB) - spoB;
      const bool soA = moA > 1.0f;
      const bool soB = moB > 1.0f;
      spoA = soA ? 1.0f : 0.0f;
      spoB = soB ? 1.0f : 0.0f;
      cntA += spoA;
      cntB += spoB;
    }

    if (l < NC) {
      out[bA * NC + l] = cntA;
      out[bB * NC + l] = cntB;
    }
  }
#undef LOAD8
#undef ADD8
#undef OLOAD8
#undef OADD8
}

// ---------------------------------------------------------------------------
extern "C" void kernel_launch(void* const* d_in, const int* in_sizes, int n_in,
                              void* d_out, int out_size, void* d_ws,
                              size_t ws_size, hipStream_t stream) {
  const float* x  = (const float*)d_in[0];
  const float* W1 = (const float*)d_in[1];
  const float* b1 = (const float*)d_in[2];
  const float* W2 = (const float*)d_in[3];
  const float* b2 = (const float*)d_in[4];
  const float* Wo = (const float*)d_in[5];
  const float* bo = (const float*)d_in[6];
  const int* nsp  = (const int*)d_in[7];
  float* outp = (float*)d_out;

  // ws layout: cur1 (16384*256 f) | W2T (32768 f) | WoT (1280 f)
  float* cur1 = (float*)d_ws;
  float* W2Tg = cur1 + (size_t)B_TOT * H1;
  float* WoTg = W2Tg + H1 * H2;

  gemm1_kernel<<<B_TOT / 16, 256, 0, stream>>>(x, W1, b1, cur1);
  transpose_kernel<<<(H2 * H1 + NC * H2 + 1023) / 1024, 1024, 0, stream>>>(
      W2, Wo, W2Tg, WoTg);

  hipFuncSetAttribute((const void*)snn_kernel,
                      hipFuncAttributeMaxDynamicSharedMemorySize, LDS_BYTES);
  snn_kernel<<<256, 1024, LDS_BYTES, stream>>>(cur1, W2Tg, WoTg, b2, bo, nsp,
                                               outp);
}